// Round 2
// baseline (210.138 us; speedup 1.0000x reference)
//
#include <hip/hip_runtime.h>
#include <hip/hip_bf16.h>
#include <stdint.h>

#define NP 30000
#define BBINS 80
#define INCH 16
#define OUTCH 32
#define KDIM 1280       // BBINS*INCH
#define NDIM 512        // OUTCH*TBINS
#define KSTEPS 40       // KDIM/32
#define NROWS (NP * BBINS)   // 2,400,000
#define RPT 4                // gather rows per thread
#define RSTRIDE (NROWS / RPT)  // 600,000

typedef __bf16 bf16x8 __attribute__((ext_vector_type(8)));
typedef __bf16 bf16x4 __attribute__((ext_vector_type(4)));
typedef float f32x4 __attribute__((ext_vector_type(4)));

__device__ __forceinline__ void async_ld16(const void* g, void* l) {
    __builtin_amdgcn_global_load_lds(
        (const __attribute__((address_space(1))) unsigned int*)g,
        (__attribute__((address_space(3))) unsigned int*)l,
        16, 0, 0);
}

// ---------------------------------------------------------------------------
// Prep: PW[kc][n][qs][e] bf16 with chunk-XOR swizzle qs ^ ((n>>1)&3), where
// lw[k][n] = W[(b+5t)%80][c][o], k=b*16+c, n=o*16+t.
// Swizzle spreads 16 consecutive-n lanes over all 8 LDS 16B-bank-groups
// (2 lanes each = conflict-free b128 reads; measured 0 conflicts in R1).
// ---------------------------------------------------------------------------
__global__ void prep_weights(const float* __restrict__ w, __bf16* __restrict__ pw) {
    int gid = blockIdx.x * 256 + threadIdx.x;           // 655360 total
    int e  = gid & 7;
    int qs = (gid >> 3) & 3;
    int n  = (gid >> 5) & 511;
    int kc = gid >> 14;                                  // 0..39
    int kp = kc * 32 + ((qs ^ ((n >> 1) & 3)) << 3) + e; // 0..1279
    int b = kp >> 4, c = kp & 15;
    int o = n >> 4,  t = n & 15;
    int bid = (b + 5 * t) % BBINS;
    pw[gid] = (__bf16)w[(bid * INCH + c) * OUTCH + o];
}

// ---------------------------------------------------------------------------
// Gather: FOUR lanes per (patch,bin) row (lane-quad member q loads channels
// [4q,4q+4)), and FOUR rows per thread (strided by RSTRIDE so every access
// pattern matches the 1-row version). 12 x-gathers + 24 meta loads in
// flight per thread: 4x the MLP of the latency-bound 1-row version.
// ---------------------------------------------------------------------------
__global__ __launch_bounds__(256) void gather_h(
    const float* __restrict__ x,
    const int*   __restrict__ cidx,
    const float* __restrict__ cval,
    __bf16* __restrict__ h) {
    const int gid = blockIdx.x * 256 + threadIdx.x;      // 2,400,000 total
    const int rb = gid >> 2;                             // base row 0..RSTRIDE-1
    const int q  = gid & 3;                              // channel quad

    int   i0[RPT], i1[RPT], i2[RPT];
    float v0[RPT], v1[RPT], v2[RPT];
#pragma unroll
    for (int k = 0; k < RPT; ++k) {
        const int r3 = (rb + k * RSTRIDE) * 3;
        i0[k] = cidx[r3 + 0]; i1[k] = cidx[r3 + 1]; i2[k] = cidx[r3 + 2];
        v0[k] = cval[r3 + 0]; v1[k] = cval[r3 + 1]; v2[k] = cval[r3 + 2];
    }
    float4 a[RPT], b[RPT], c[RPT];
#pragma unroll
    for (int k = 0; k < RPT; ++k) {
        a[k] = *(const float4*)(x + (size_t)i0[k] * 16 + q * 4);
        b[k] = *(const float4*)(x + (size_t)i1[k] * 16 + q * 4);
        c[k] = *(const float4*)(x + (size_t)i2[k] * 16 + q * 4);
    }
#pragma unroll
    for (int k = 0; k < RPT; ++k) {
        bf16x4 hv;
        hv[0] = (__bf16)(v0[k] * a[k].x + v1[k] * b[k].x + v2[k] * c[k].x);
        hv[1] = (__bf16)(v0[k] * a[k].y + v1[k] * b[k].y + v2[k] * c[k].y);
        hv[2] = (__bf16)(v0[k] * a[k].z + v1[k] * b[k].z + v2[k] * c[k].z);
        hv[3] = (__bf16)(v0[k] * a[k].w + v1[k] * b[k].w + v2[k] * c[k].w);
        *(bf16x4*)((char*)h + (size_t)(rb + k * RSTRIDE) * 32 + q * 8) = hv;
    }
}

// ---------------------------------------------------------------------------
// GEMM + max-over-t.  Block: 256 threads (4 waves), tile 128 rows x 256 cols.
// Wave grid 2x2; wave tile 64x128 = 4x8 mfma_f32_16x16x32_bf16.
//
// Structure = proven round-0 skeleton (stage -> sync -> compute; explicit
// dbuf/asm pipeline measured -45% in R1, reverted). Changes vs round 0:
//  * A is NOT staged in LDS: the MFMA A-fragment pattern (lane ml+16q reads
//    row ml, 16B chunk q) is itself perfectly coalesced (16 full 64B lines
//    per instr), so af[] loads go global->VGPR directly. This cuts LDS
//    traffic per block-step from 72KB to 48KB, drops 2 of 6 staged loads
//    from the vmcnt drain, and eliminates the old 8-way A-read conflicts.
//  * B keeps the R1-proven conflict-free swizzle (0 conflicts measured),
//    via pre-swizzled pw + swizzled ds_read offsets; LDS now 16KB.
// ---------------------------------------------------------------------------
__global__ __launch_bounds__(256, 2) void gemm_max(
    const __bf16* __restrict__ h,
    const __bf16* __restrict__ pw,
    float* __restrict__ out) {

    __shared__ __align__(16) __bf16 Blds[256 * 32];      // 16 KB (n stride 64 B)

    const int bid = blockIdx.x;
    const int m    = (bid >> 4) * 8 + (bid & 7);         // 0..239
    const int ncol = (bid >> 3) & 1;                     // 0/1
    if (m >= 235) return;                                // 10 dead pad blocks
    const int mbase = m * 128;

    const int tid  = threadIdx.x;
    const int lane = tid & 63;
    const int wave = tid >> 6;
    const int wave_mrow = wave >> 1;     // 0..1
    const int wave_ncol = wave & 1;      // 0..1

    const int ml = lane & 15, q = lane >> 4;
    const int f = (ml >> 1) & 3;                         // bank-group swizzle
    int b_off[8];
#pragma unroll
    for (int j = 0; j < 8; ++j) {
        int nl = wave_ncol * 128 + j * 16 + ml;
        b_off[j] = nl * 64 + ((q ^ f) << 4);
    }

    // Direct global A-fragment base pointers (row clamped for last tile).
    const char* aPtr[4];
#pragma unroll
    for (int i = 0; i < 4; ++i) {
        int r = mbase + wave_mrow * 64 + i * 16 + ml;
        if (r > NP - 1) r = NP - 1;
        aPtr[i] = (const char*)h + (size_t)r * 2560 + q * 16;
    }

    f32x4 acc[4][8];
#pragma unroll
    for (int i = 0; i < 4; ++i)
#pragma unroll
        for (int j = 0; j < 8; ++j)
            acc[i][j] = (f32x4){0.f, 0.f, 0.f, 0.f};

    const char* pwB = (const char*)pw + ncol * 16384 + tid * 16;
    char* bDst = (char*)Blds + tid * 16;

#define STAGE_B(kc_)                                                         \
    do {                                                                     \
        const char* bs_ = pwB + (kc_) * 32768;                               \
        async_ld16(bs_ + 0 * 4096, bDst + 0 * 4096);                         \
        async_ld16(bs_ + 1 * 4096, bDst + 1 * 4096);                         \
        async_ld16(bs_ + 2 * 4096, bDst + 2 * 4096);                         \
        async_ld16(bs_ + 3 * 4096, bDst + 3 * 4096);                         \
    } while (0)

    bf16x8 af[4];
    STAGE_B(0);
#pragma unroll
    for (int i = 0; i < 4; ++i)
        af[i] = *(const bf16x8*)(aPtr[i]);
    __syncthreads();

    for (int kc = 0; kc < KSTEPS; ++kc) {
        bf16x8 bfr[8];
#pragma unroll
        for (int j = 0; j < 8; ++j)
            bfr[j] = *(const bf16x8*)((const char*)Blds + b_off[j]);
#pragma unroll
        for (int i = 0; i < 4; ++i)
#pragma unroll
            for (int j = 0; j < 8; ++j)
                acc[i][j] = __builtin_amdgcn_mfma_f32_16x16x32_bf16(
                    af[i], bfr[j], acc[i][j], 0, 0, 0);

        if (kc + 1 < KSTEPS) {
            __syncthreads();                 // all waves done reading Blds
            STAGE_B(kc + 1);
#pragma unroll
            for (int i = 0; i < 4; ++i)
                af[i] = *(const bf16x8*)(aPtr[i] + (kc + 1) * 64);
            __syncthreads();                 // drains vmcnt: B + A landed
        }
    }
#undef STAGE_B

    const int rgrp = lane >> 4;
    const int tl   = lane & 15;
#pragma unroll
    for (int i = 0; i < 4; ++i) {
#pragma unroll
        for (int j = 0; j < 8; ++j) {
            float v0 = acc[i][j][0], v1 = acc[i][j][1];
            float v2 = acc[i][j][2], v3 = acc[i][j][3];
#pragma unroll
            for (int off = 1; off < 16; off <<= 1) {
                v0 = fmaxf(v0, __shfl_xor(v0, off));
                v1 = fmaxf(v1, __shfl_xor(v1, off));
                v2 = fmaxf(v2, __shfl_xor(v2, off));
                v3 = fmaxf(v3, __shfl_xor(v3, off));
            }
            if (tl == 0) {
                const int o  = ncol * 16 + wave_ncol * 8 + j;
                const int pr = mbase + wave_mrow * 64 + i * 16 + rgrp * 4;
                if (pr + 0 < NP) out[(pr + 0) * 32 + o] = v0;
                if (pr + 1 < NP) out[(pr + 1) * 32 + o] = v1;
                if (pr + 2 < NP) out[(pr + 2) * 32 + o] = v2;
                if (pr + 3 < NP) out[(pr + 3) * 32 + o] = v3;
            }
        }
    }
}

extern "C" void kernel_launch(void* const* d_in, const int* in_sizes, int n_in,
                              void* d_out, int out_size, void* d_ws, size_t ws_size,
                              hipStream_t stream) {
    const float* x    = (const float*)d_in[0];
    const int*   cidx = (const int*)d_in[1];
    const float* cval = (const float*)d_in[2];
    const float* w    = (const float*)d_in[3];
    float* out = (float*)d_out;

    __bf16* pw = (__bf16*)d_ws;                               // 1.31 MB
    __bf16* h  = (__bf16*)((char*)d_ws + (2 << 20));          // 76.8 MB @ +2MB

    hipLaunchKernelGGL(prep_weights, dim3(2560), dim3(256), 0, stream, w, pw);
    hipLaunchKernelGGL(gather_h, dim3(NROWS / 256), dim3(256), 0, stream,
                       x, cidx, cval, h);
    hipLaunchKernelGGL(gemm_max, dim3(480), dim3(256), 0, stream,
                       h, (const __bf16*)pw, out);
}

// Round 3
// 188.063 us; speedup vs baseline: 1.1174x; 1.1174x over previous
//
#include <hip/hip_runtime.h>
#include <hip/hip_bf16.h>
#include <stdint.h>

#define NP 30000
#define BBINS 80
#define INCH 16
#define OUTCH 32
#define KDIM 1280       // BBINS*INCH
#define NDIM 512        // OUTCH*TBINS
#define KSTEPS 40       // KDIM/32
#define NROWS (NP * BBINS)   // 2,400,000

typedef __bf16 bf16x8 __attribute__((ext_vector_type(8)));
typedef __bf16 bf16x4 __attribute__((ext_vector_type(4)));
typedef float f32x4 __attribute__((ext_vector_type(4)));

__device__ __forceinline__ void async_ld16(const void* g, void* l) {
    __builtin_amdgcn_global_load_lds(
        (const __attribute__((address_space(1))) unsigned int*)g,
        (__attribute__((address_space(3))) unsigned int*)l,
        16, 0, 0);
}

// ---------------------------------------------------------------------------
// Prep: PW[kc][n][qs][e] bf16 with chunk-XOR swizzle qs ^ ((n>>1)&3), where
// lw[k][n] = W[(b+5t)%80][c][o], k=b*16+c, n=o*16+t.
// Swizzle spreads each 16-lane b128 read phase over all 8 LDS 16B
// bank-groups exactly 2x (2-way = free). Measured: 0 conflicts (R1/R2).
// ---------------------------------------------------------------------------
__global__ void prep_weights(const float* __restrict__ w, __bf16* __restrict__ pw) {
    int gid = blockIdx.x * 256 + threadIdx.x;           // 655360 total
    int e  = gid & 7;
    int qs = (gid >> 3) & 3;
    int n  = (gid >> 5) & 511;
    int kc = gid >> 14;                                  // 0..39
    int kp = kc * 32 + ((qs ^ ((n >> 1) & 3)) << 3) + e; // 0..1279
    int b = kp >> 4, c = kp & 15;
    int o = n >> 4,  t = n & 15;
    int bid = (b + 5 * t) % BBINS;
    pw[gid] = (__bf16)w[(bid * INCH + c) * OUTCH + o];
}

// ---------------------------------------------------------------------------
// Gather: FOUR lanes per (patch,bin) row; lane-quad member q loads channels
// [4q,4q+4) of each of the 3 support rows. One row per thread (RPT=1):
// measured 58 us; the RPT=4 variant measured 75.5 us (less TLP, no gain in
// MLP that 8 waves/SIMD weren't already providing). Reverted to RPT=1.
// ---------------------------------------------------------------------------
__global__ __launch_bounds__(256) void gather_h(
    const float* __restrict__ x,
    const int*   __restrict__ cidx,
    const float* __restrict__ cval,
    __bf16* __restrict__ h) {
    const int gid = blockIdx.x * 256 + threadIdx.x;      // 9,600,000 total
    const int r = gid >> 2;                              // row 0..NROWS-1
    const int q = gid & 3;                               // channel quad
    const int r3 = r * 3;
    const int i0 = cidx[r3 + 0], i1 = cidx[r3 + 1], i2 = cidx[r3 + 2];
    const float v0 = cval[r3 + 0], v1 = cval[r3 + 1], v2 = cval[r3 + 2];
    const float4 a = *(const float4*)(x + (size_t)i0 * 16 + q * 4);
    const float4 b = *(const float4*)(x + (size_t)i1 * 16 + q * 4);
    const float4 c = *(const float4*)(x + (size_t)i2 * 16 + q * 4);
    bf16x4 hv;
    hv[0] = (__bf16)(v0 * a.x + v1 * b.x + v2 * c.x);
    hv[1] = (__bf16)(v0 * a.y + v1 * b.y + v2 * c.y);
    hv[2] = (__bf16)(v0 * a.z + v1 * b.z + v2 * c.z);
    hv[3] = (__bf16)(v0 * a.w + v1 * b.w + v2 * c.w);
    *(bf16x4*)((char*)h + (size_t)gid * 8) = hv;
}

// ---------------------------------------------------------------------------
// GEMM + max-over-t.  Block: 256 threads (4 waves), tile 128 rows x 256 cols.
// Wave grid 2x2; wave tile 64x128 = 4x8 mfma_f32_16x16x32_bf16.
//
// Structure = round-0 skeleton EXACTLY (stage A+B -> sync -> ds_read+MFMA ->
// sync). Measured: explicit dbuf/asm pipeline -45% (R1), A-direct-from-
// global -16% (R2) -- both reverted. Only delta vs round 0: conflict-free
// swizzles on BOTH operands (R0 paid 3.6M conflict cycles; R1/R2 measured 0):
//  * B: pre-swizzled in prep_weights, read offset q^((nl>>1)&3).
//  * A: pre-swizzled global SOURCE (global_load_lds writes linearly),
//    read offset q^((row>>1)&3). Refcheck-passed in R1.
// ---------------------------------------------------------------------------
__global__ __launch_bounds__(256, 2) void gemm_max(
    const __bf16* __restrict__ h,
    const __bf16* __restrict__ pw,
    float* __restrict__ out) {

    __shared__ __align__(16) __bf16 Alds[128 * 32];      // 8 KB  (row stride 64 B)
    __shared__ __align__(16) __bf16 Blds[256 * 32];      // 16 KB (n stride 64 B)

    const int bid = blockIdx.x;
    const int m    = (bid >> 4) * 8 + (bid & 7);         // 0..239
    const int ncol = (bid >> 3) & 1;                     // 0/1
    if (m >= 235) return;                                // 10 dead pad blocks
    const int mbase = m * 128;

    const int tid  = threadIdx.x;
    const int lane = tid & 63;
    const int wave = tid >> 6;
    const int wave_mrow = wave >> 1;     // 0..1
    const int wave_ncol = wave & 1;      // 0..1

    const int ml = lane & 15, q = lane >> 4;
    const int f = (ml >> 1) & 3;                         // bank-group swizzle
    int a_off[4], b_off[8];
#pragma unroll
    for (int i = 0; i < 4; ++i)
        a_off[i] = (wave_mrow * 64 + i * 16 + ml) * 64 + ((q ^ f) << 4);
#pragma unroll
    for (int j = 0; j < 8; ++j) {
        int nl = wave_ncol * 128 + j * 16 + ml;
        b_off[j] = nl * 64 + ((q ^ f) << 4);
    }

    f32x4 acc[4][8];
#pragma unroll
    for (int i = 0; i < 4; ++i)
#pragma unroll
        for (int j = 0; j < 8; ++j)
            acc[i][j] = (f32x4){0.f, 0.f, 0.f, 0.f};

    const char* hB  = (const char*)h;
    const char* pwB = (const char*)pw + ncol * 16384 + tid * 16;
    int rg0 = mbase + (tid >> 2);        // rows 0..63 of tile
    int rg1 = rg0 + 64;                  // rows 64..127
    if (rg0 > NP - 1) rg0 = NP - 1;
    if (rg1 > NP - 1) rg1 = NP - 1;
    // pre-swizzled source chunk: LDS slot (tid&3) of row (tid>>2) must hold
    // source chunk (tid&3) ^ ((row>>1)&3) = (tid&3) ^ ((tid>>3)&3)
    const int swz = ((tid & 3) ^ ((tid >> 3) & 3)) * 16;
    const char* aSrc0 = hB + (size_t)rg0 * 2560 + swz;
    const char* aSrc1 = hB + (size_t)rg1 * 2560 + swz;
    char* aDst0 = (char*)Alds + tid * 16;
    char* aDst1 = aDst0 + 4096;
    char* bDst  = (char*)Blds + tid * 16;

    for (int kc = 0; kc < KSTEPS; ++kc) {
        const char* bs = pwB + kc * 32768;
#pragma unroll
        for (int i = 0; i < 4; ++i)
            async_ld16(bs + i * 4096, bDst + i * 4096);
        async_ld16(aSrc0 + kc * 64, aDst0);
        async_ld16(aSrc1 + kc * 64, aDst1);
        __syncthreads();

        bf16x8 af[4], bfr[8];
#pragma unroll
        for (int i = 0; i < 4; ++i)
            af[i] = *(const bf16x8*)((const char*)Alds + a_off[i]);
#pragma unroll
        for (int j = 0; j < 8; ++j)
            bfr[j] = *(const bf16x8*)((const char*)Blds + b_off[j]);
#pragma unroll
        for (int i = 0; i < 4; ++i)
#pragma unroll
            for (int j = 0; j < 8; ++j)
                acc[i][j] = __builtin_amdgcn_mfma_f32_16x16x32_bf16(
                    af[i], bfr[j], acc[i][j], 0, 0, 0);
        __syncthreads();
    }

    const int rgrp = lane >> 4;
    const int tl   = lane & 15;
#pragma unroll
    for (int i = 0; i < 4; ++i) {
#pragma unroll
        for (int j = 0; j < 8; ++j) {
            float v0 = acc[i][j][0], v1 = acc[i][j][1];
            float v2 = acc[i][j][2], v3 = acc[i][j][3];
#pragma unroll
            for (int off = 1; off < 16; off <<= 1) {
                v0 = fmaxf(v0, __shfl_xor(v0, off));
                v1 = fmaxf(v1, __shfl_xor(v1, off));
                v2 = fmaxf(v2, __shfl_xor(v2, off));
                v3 = fmaxf(v3, __shfl_xor(v3, off));
            }
            if (tl == 0) {
                const int o  = ncol * 16 + wave_ncol * 8 + j;
                const int pr = mbase + wave_mrow * 64 + i * 16 + rgrp * 4;
                if (pr + 0 < NP) out[(pr + 0) * 32 + o] = v0;
                if (pr + 1 < NP) out[(pr + 1) * 32 + o] = v1;
                if (pr + 2 < NP) out[(pr + 2) * 32 + o] = v2;
                if (pr + 3 < NP) out[(pr + 3) * 32 + o] = v3;
            }
        }
    }
}

extern "C" void kernel_launch(void* const* d_in, const int* in_sizes, int n_in,
                              void* d_out, int out_size, void* d_ws, size_t ws_size,
                              hipStream_t stream) {
    const float* x    = (const float*)d_in[0];
    const int*   cidx = (const int*)d_in[1];
    const float* cval = (const float*)d_in[2];
    const float* w    = (const float*)d_in[3];
    float* out = (float*)d_out;

    __bf16* pw = (__bf16*)d_ws;                               // 1.31 MB
    __bf16* h  = (__bf16*)((char*)d_ws + (2 << 20));          // 76.8 MB @ +2MB

    hipLaunchKernelGGL(prep_weights, dim3(2560), dim3(256), 0, stream, w, pw);
    hipLaunchKernelGGL(gather_h, dim3(NROWS * 4 / 256), dim3(256), 0, stream,
                       x, cidx, cval, h);
    hipLaunchKernelGGL(gemm_max, dim3(480), dim3(256), 0, stream,
                       h, (const __bf16*)pw, out);
}